// Round 7
// baseline (739.804 us; speedup 1.0000x reference)
//
#include <hip/hip_runtime.h>

// EdgeNet: BN -> inputnet MLP -> EdgeConv(linearized) -> mean-pool -> output MLP
// N=50000, E=1.6M, D=13, H=32, G=128. All I/O float32.
// EdgeConv restructure: per-node A = feat@(Wtop-Wbot)+b1, B = feat@Wbot (bf16);
// per-edge h = relu(A[dst]+B[src]); msg = tanh(h@W2+b2) via MFMA 16x16x32 bf16.
// R7: edges counting-sorted by graph id g=batch[dst] (hist/scan/scatter), then
//     k_edge accumulates messages in per-lane REGISTER accumulators tagged by
//     graph, flushing f32 atomics to gacc only on tag change / kernel end.
//     Removes the 25.6M per-edge atomics + 100MB write stream + Hn + k_pool.
//     Correctness independent of sort order (tags handle any sequence).

typedef __attribute__((ext_vector_type(4))) float floatx4;
typedef __attribute__((ext_vector_type(8))) short short8;

__device__ __forceinline__ unsigned short f2bf(float f) {
    unsigned int u = __float_as_uint(f);
    u += 0x7FFFu + ((u >> 16) & 1u);   // RTNE
    return (unsigned short)(u >> 16);
}
__device__ __forceinline__ float bf2f(unsigned short u) {
    return __uint_as_float(((unsigned int)u) << 16);
}
__device__ __forceinline__ float fast_tanh(float x) {
    float ax = fminf(fabsf(x), 20.0f);
    float t = __expf(-2.0f * ax);
    float r = (1.0f - t) / (1.0f + t);
    return copysignf(r, x);
}
__device__ __forceinline__ float fast_sigmoid(float x) {
    float xc = fminf(fmaxf(x, -30.f), 30.f);
    return 1.0f / (1.0f + __expf(-xc));
}

// ---------------- K1: BatchNorm statistics ----------------
__global__ __launch_bounds__(256) void k_bnstat(const float* __restrict__ x,
                                                int N, float* __restrict__ bns) {
    int tid = blockIdx.x * blockDim.x + threadIdx.x;
    int stride = gridDim.x * blockDim.x;
    float s[13], q[13];
#pragma unroll
    for (int d = 0; d < 13; d++) { s[d] = 0.f; q[d] = 0.f; }
    for (int n = tid; n < N; n += stride) {
        const float* row = x + (size_t)n * 13;
#pragma unroll
        for (int d = 0; d < 13; d++) { float f = row[d]; s[d] += f; q[d] += f * f; }
    }
#pragma unroll
    for (int d = 0; d < 13; d++) {
        for (int off = 32; off > 0; off >>= 1) {
            s[d] += __shfl_down(s[d], off, 64);
            q[d] += __shfl_down(q[d], off, 64);
        }
    }
    if ((threadIdx.x & 63) == 0) {
#pragma unroll
        for (int d = 0; d < 13; d++) {
            unsafeAtomicAdd(&bns[d], s[d]);
            unsafeAtomicAdd(&bns[13 + d], q[d]);
        }
    }
}

// ---------------- K1b: finalize scale/shift ----------------
__global__ void k_bnfin(const float* __restrict__ bns, const float* __restrict__ g,
                        const float* __restrict__ b, float* __restrict__ scl, float invN) {
    int d = threadIdx.x;
    if (d < 13) {
        float mu  = bns[d] * invN;
        float var = fmaxf(bns[13 + d] * invN - mu * mu, 0.f);
        float sc  = g[d] / sqrtf(var + 1e-5f);
        scl[d]      = sc;
        scl[16 + d] = b[d] - mu * sc;
    }
}

// ---------------- K2: per-node phase (unchanged from R6) ----------------
#define FP 72  // feat LDS row stride in shorts (64 + 8 pad)
#define WP 72  // WcatT LDS row stride in shorts
__global__ __launch_bounds__(128) void k_node(
    const float* __restrict__ x, const int* __restrict__ batch,
    const float* __restrict__ in_w1, const float* __restrict__ in_b1,
    const float* __restrict__ in_w2, const float* __restrict__ in_b2,
    const float* __restrict__ conv_w1, const float* __restrict__ conv_b1,
    const float* __restrict__ scl,
    unsigned short* __restrict__ A, unsigned short* __restrict__ Bm,
    float* __restrict__ gacc, int N) {
    __shared__ float sW1[13 * 32], sB1[32], sW2[32 * 32], sB2[32];
    __shared__ unsigned short sWcatT[128 * WP];
    __shared__ unsigned short sFeat[128 * FP];
    int tid = threadIdx.x;

    for (int i = tid; i < 13 * 32; i += 128) sW1[i] = in_w1[i];
    if (tid < 32) { sB1[tid] = in_b1[tid]; sB2[tid] = in_b2[tid]; }
    for (int i = tid; i < 32 * 32; i += 128) sW2[i] = in_w2[i];
    for (int i = tid; i < 128 * 64; i += 128) {
        int c = i >> 6, k = i & 63;
        float v = 0.f;
        if (k < 45) {
            int cc = c & 63;
            float bot = conv_w1[(45 + k) * 64 + cc];
            v = (c < 64) ? (conv_w1[k * 64 + cc] - bot) : bot;
        }
        sWcatT[c * WP + k] = f2bf(v);
    }
    __syncthreads();

    int n = blockIdx.x * 128 + tid;
    bool valid = (n < N);
    int nl = valid ? n : (N - 1);

    float X[13];
#pragma unroll
    for (int d = 0; d < 13; d++)
        X[d] = x[(size_t)nl * 13 + d] * scl[d] + scl[16 + d];
    float h1[32];
#pragma unroll
    for (int j = 0; j < 32; j++) {
        float acc = sB1[j];
#pragma unroll
        for (int d = 0; d < 13; d++) acc += X[d] * sW1[d * 32 + j];
        h1[j] = fmaxf(acc, 0.f);
    }
    float h2[32];
#pragma unroll
    for (int j = 0; j < 32; j++) {
        float acc = sB2[j];
#pragma unroll
        for (int k = 0; k < 32; k++) acc += h1[k] * sW2[k * 32 + j];
        h2[j] = fast_tanh(acc);
    }

    unsigned int fw[16];
#pragma unroll
    for (int i = 0; i < 16; i++) fw[i] = 0;
    if (valid) {
#pragma unroll
        for (int i = 0; i < 16; i++)
            fw[i] = (unsigned)f2bf(h2[2 * i]) | ((unsigned)f2bf(h2[2 * i + 1]) << 16);
    }
    unsigned int xw[7];
#pragma unroll
    for (int i = 0; i < 7; i++) xw[i] = 0;
    if (valid) {
#pragma unroll
        for (int i = 0; i < 6; i++)
            xw[i] = (unsigned)f2bf(X[2 * i]) | ((unsigned)f2bf(X[2 * i + 1]) << 16);
        xw[6] = (unsigned)f2bf(X[12]);
    }
    {
        unsigned short* row = sFeat + tid * FP;
        ((uint4*)row)[0] = make_uint4(fw[0], fw[1], fw[2], fw[3]);
        ((uint4*)row)[1] = make_uint4(fw[4], fw[5], fw[6], fw[7]);
        ((uint4*)row)[2] = make_uint4(fw[8], fw[9], fw[10], fw[11]);
        ((uint4*)row)[3] = make_uint4(fw[12], fw[13], fw[14], fw[15]);
        ((uint4*)row)[4] = make_uint4(xw[0], xw[1], xw[2], xw[3]);
        ((uint4*)row)[5] = make_uint4(xw[4], xw[5], xw[6], 0u);
        ((uint4*)row)[6] = make_uint4(0u, 0u, 0u, 0u);
        ((uint4*)row)[7] = make_uint4(0u, 0u, 0u, 0u);
    }

    {
        int g = valid ? batch[n] : -1;
        unsigned long long uni = __ballot(g == __shfl(g, 0, 64));
        if (uni == ~0ull && g >= 0) {
            float red[14];
#pragma unroll
            for (int d = 0; d < 13; d++) red[d] = X[d];
            red[13] = 1.0f;
#pragma unroll
            for (int d = 0; d < 14; d++)
                for (int off = 32; off > 0; off >>= 1)
                    red[d] += __shfl_down(red[d], off, 64);
            if ((tid & 63) == 0) {
#pragma unroll
                for (int d = 0; d < 13; d++) unsafeAtomicAdd(&gacc[g * 46 + 32 + d], red[d]);
                unsafeAtomicAdd(&gacc[g * 46 + 45], red[13]);
            }
        } else if (valid) {
#pragma unroll
            for (int d = 0; d < 13; d++) unsafeAtomicAdd(&gacc[g * 46 + 32 + d], X[d]);
            unsafeAtomicAdd(&gacc[g * 46 + 45], 1.0f);
        }
    }
    __syncthreads();

    int lane = tid & 63;
    int w = tid >> 6;
    int q = lane >> 4;
    int m = lane & 15;

    short8 wf[2][8];
#pragma unroll
    for (int ks = 0; ks < 2; ks++)
#pragma unroll
        for (int t = 0; t < 8; t++) {
            wf[ks][t] = *(const short8*)(sWcatT + (t * 16 + m) * WP + ks * 32 + q * 8);
        }
    float cb1v[4];
#pragma unroll
    for (int t = 0; t < 4; t++) cb1v[t] = conv_b1[t * 16 + m];

    int base = blockIdx.x * 128 + w * 64;
#pragma unroll
    for (int tile = 0; tile < 4; tile++) {
        const unsigned short* ar = sFeat + (w * 64 + tile * 16 + m) * FP;
        short8 a0 = *(const short8*)(ar + q * 8);
        short8 a1 = *(const short8*)(ar + 32 + q * 8);
        floatx4 c[8];
#pragma unroll
        for (int t = 0; t < 8; t++) {
            floatx4 z = {0.f, 0.f, 0.f, 0.f};
            c[t] = __builtin_amdgcn_mfma_f32_16x16x32_bf16(a0, wf[0][t], z, 0, 0, 0);
            c[t] = __builtin_amdgcn_mfma_f32_16x16x32_bf16(a1, wf[1][t], c[t], 0, 0, 0);
        }
#pragma unroll
        for (int r = 0; r < 4; r++) {
            int row = base + tile * 16 + (q << 2) + r;
            if (row < N) {
#pragma unroll
                for (int t = 0; t < 4; t++)
                    A[(size_t)row * 64 + t * 16 + m] = f2bf(c[t][r] + cb1v[t]);
#pragma unroll
                for (int t = 4; t < 8; t++)
                    Bm[(size_t)row * 64 + (t - 4) * 16 + m] = f2bf(c[t][r]);
            }
        }
    }
}

// ---------------- K3a: histogram of edge graph ids ----------------
__global__ __launch_bounds__(256) void k_ghist(const int* __restrict__ ei,
                                               const int* __restrict__ batch,
                                               int* __restrict__ bins, int E) {
    __shared__ int sh[128];
    int tid = threadIdx.x;
    if (tid < 128) sh[tid] = 0;
    __syncthreads();
    int idx = blockIdx.x * blockDim.x + tid;
    int stride = gridDim.x * blockDim.x;
    for (int e = idx; e < E; e += stride) {
        int g = batch[ei[E + e]];   // graph of dst
        atomicAdd(&sh[g], 1);
    }
    __syncthreads();
    if (tid < 128 && sh[tid] > 0) atomicAdd(&bins[tid], sh[tid]);
}

// ---------------- K3b: exclusive scan -> cursors (stride 16 ints) -----------
__global__ void k_gscan(const int* __restrict__ bins, int* __restrict__ cursor) {
    __shared__ int sb[128];
    int t = threadIdx.x;
    int v0 = bins[t];
    sb[t] = v0;
    __syncthreads();
    for (int off = 1; off < 128; off <<= 1) {
        int v = (t >= off) ? sb[t - off] : 0;
        __syncthreads();
        sb[t] += v;
        __syncthreads();
    }
    cursor[t * 16] = sb[t] - v0;   // exclusive
}

// ---------------- K3c: scatter edges into graph-sorted order ----------------
__global__ __launch_bounds__(256) void k_gscatter(const int* __restrict__ ei,
                                                  const int* __restrict__ batch,
                                                  int* __restrict__ cursor,
                                                  int* __restrict__ es, int* __restrict__ ed,
                                                  int* __restrict__ eg, int E) {
    int idx = blockIdx.x * blockDim.x + threadIdx.x;
    int stride = gridDim.x * blockDim.x;
    for (int e = idx; e < E; e += stride) {
        int s = ei[e];
        int d = ei[E + e];
        int g = batch[d];
        int pos = atomicAdd(&cursor[g * 16], 1);
        es[pos] = s;
        ed[pos] = d;
        eg[pos] = g;
    }
}

// ---------------- K4: edge phase (MFMA + register graph accumulation) -------
// 16 edges per wave-group. A-frag: h[m][k=ks*32+q*8+j]. B-frags: W2 cols
// interleaved even/odd (tile0 -> 2n, tile1 -> 2n+1) so lane (q,m)'s C pair
// c0[r],c1[r] = channels (2m,2m+1) of edge e0+4q+r. Edges sorted by graph:
// accumulate per-lane sums tagged by graph, flush on tag change / end.
__global__ __launch_bounds__(256) void k_edge(
    const int* __restrict__ es, const int* __restrict__ ed, const int* __restrict__ eg,
    const unsigned short* __restrict__ A, const unsigned short* __restrict__ Bm,
    const float* __restrict__ conv_w2, const float* __restrict__ conv_b2,
    float* __restrict__ gacc, int E) {
    int lane = threadIdx.x & 63;
    int wid  = blockIdx.x * (blockDim.x >> 6) + (threadIdx.x >> 6);
    int nw   = gridDim.x * (blockDim.x >> 6);
    int q = lane >> 4;
    int m = lane & 15;

    short8 wf[2][2];
#pragma unroll
    for (int s = 0; s < 2; s++)
#pragma unroll
        for (int t = 0; t < 2; t++)
#pragma unroll
            for (int j = 0; j < 8; j++)
                wf[s][t][j] = (short)f2bf(conv_w2[(s * 32 + q * 8 + j) * 32 + 2 * m + t]);
    float cb2a = conv_b2[2 * m];
    float cb2b = conv_b2[2 * m + 1];

    int NG = E >> 4;
    int span = (NG + nw - 1) / nw;
    int gI0 = wid * span;
    int gI1 = min(gI0 + span, NG);

    int   tag[4];
    float ac0[4], ac1[4];
#pragma unroll
    for (int r = 0; r < 4; r++) { tag[r] = -1; ac0[r] = 0.f; ac1[r] = 0.f; }

    for (int gI = gI0; gI < gI1; gI++) {
        int e0 = gI << 4;
        int vd = ed[e0 + m];
        int vs = es[e0 + m];
        uint4 gts = *(const uint4*)(eg + e0 + 4 * q);
        floatx4 c0 = {0.f, 0.f, 0.f, 0.f};
        floatx4 c1 = {0.f, 0.f, 0.f, 0.f};
#pragma unroll
        for (int ks = 0; ks < 2; ks++) {
            uint4 av = *(const uint4*)(A  + (size_t)vd * 64 + ks * 32 + q * 8);
            uint4 bv = *(const uint4*)(Bm + (size_t)vs * 64 + ks * 32 + q * 8);
            unsigned au[4] = {av.x, av.y, av.z, av.w};
            unsigned bu[4] = {bv.x, bv.y, bv.z, bv.w};
            short8 ha;
#pragma unroll
            for (int i = 0; i < 4; i++) {
                float a0 = __uint_as_float(au[i] << 16);
                float a1 = __uint_as_float(au[i] & 0xffff0000u);
                float b0 = __uint_as_float(bu[i] << 16);
                float b1 = __uint_as_float(bu[i] & 0xffff0000u);
                float h0 = fmaxf(a0 + b0, 0.f);
                float h1v = fmaxf(a1 + b1, 0.f);
                ha[2 * i]     = (short)f2bf(h0);
                ha[2 * i + 1] = (short)f2bf(h1v);
            }
            c0 = __builtin_amdgcn_mfma_f32_16x16x32_bf16(ha, wf[ks][0], c0, 0, 0, 0);
            c1 = __builtin_amdgcn_mfma_f32_16x16x32_bf16(ha, wf[ks][1], c1, 0, 0, 0);
        }
        const int* gt = (const int*)&gts;
#pragma unroll
        for (int r = 0; r < 4; r++) {
            int gg = gt[r];
            float o0 = fast_tanh(c0[r] + cb2a);
            float o1 = fast_tanh(c1[r] + cb2b);
            if (gg != tag[r]) {
                if (tag[r] >= 0) {
                    unsafeAtomicAdd(&gacc[tag[r] * 46 + 2 * m], ac0[r]);
                    unsafeAtomicAdd(&gacc[tag[r] * 46 + 2 * m + 1], ac1[r]);
                }
                tag[r] = gg; ac0[r] = 0.f; ac1[r] = 0.f;
            }
            ac0[r] += o0;
            ac1[r] += o1;
        }
    }
#pragma unroll
    for (int r = 0; r < 4; r++) {
        if (tag[r] >= 0) {
            unsafeAtomicAdd(&gacc[tag[r] * 46 + 2 * m], ac0[r]);
            unsafeAtomicAdd(&gacc[tag[r] * 46 + 2 * m + 1], ac1[r]);
        }
    }

    // scalar tail (E % 16): straight to gacc
    int tail = E & 15;
    if (tail && wid == 0 && lane < tail) {
        int e = (E & ~15) + lane;
        int vd = ed[e], vs = es[e], gg = eg[e];
        float h[64];
        for (int k = 0; k < 64; k++) {
            float a = bf2f(A[(size_t)vd * 64 + k]);
            float b = bf2f(Bm[(size_t)vs * 64 + k]);
            h[k] = fmaxf(a + b, 0.f);
        }
        for (int j = 0; j < 32; j++) {
            float acc = conv_b2[j];
            for (int k = 0; k < 64; k++) acc += h[k] * conv_w2[k * 32 + j];
            unsafeAtomicAdd(&gacc[gg * 46 + j], fast_tanh(acc));
        }
    }
}

// ---------------- K5: output MLP ----------------
__global__ void k_out(const float* __restrict__ gacc,
                      const float* __restrict__ out_w1, const float* __restrict__ out_b1,
                      const float* __restrict__ out_w2, const float* __restrict__ out_b2,
                      float* __restrict__ out, int G) {
    int g = blockIdx.x * blockDim.x + threadIdx.x;
    if (g >= G) return;
    float cnt = fmaxf(gacc[g * 46 + 45], 1.0f);
    float inv = 1.0f / cnt;
    float f[45];
#pragma unroll
    for (int i = 0; i < 45; i++) f[i] = gacc[g * 46 + i] * inv;
    float h[32];
#pragma unroll
    for (int j = 0; j < 32; j++) {
        float acc = out_b1[j];
#pragma unroll
        for (int k = 0; k < 45; k++) acc += f[k] * out_w1[k * 32 + j];
        h[j] = fmaxf(acc, 0.f);
    }
    float o = out_b2[0];
#pragma unroll
    for (int j = 0; j < 32; j++) o += h[j] * out_w2[j];
    out[g] = fast_sigmoid(o);
}

extern "C" void kernel_launch(void* const* d_in, const int* in_sizes, int n_in,
                              void* d_out, int out_size, void* d_ws, size_t ws_size,
                              hipStream_t stream) {
    const float* x      = (const float*)d_in[0];
    const int*   ei     = (const int*)d_in[1];
    const int*   batch  = (const int*)d_in[2];
    const float* bn_g   = (const float*)d_in[3];
    const float* bn_b   = (const float*)d_in[4];
    const float* in_w1  = (const float*)d_in[5];
    const float* in_b1  = (const float*)d_in[6];
    const float* in_w2  = (const float*)d_in[7];
    const float* in_b2  = (const float*)d_in[8];
    const float* cw1    = (const float*)d_in[9];
    const float* cb1    = (const float*)d_in[10];
    const float* cw2    = (const float*)d_in[11];
    const float* cb2    = (const float*)d_in[12];
    const float* ow1    = (const float*)d_in[13];
    const float* ob1    = (const float*)d_in[14];
    const float* ow2    = (const float*)d_in[15];
    const float* ob2    = (const float*)d_in[16];

    int N = in_sizes[0] / 13;
    int E = in_sizes[1] / 2;
    int G = out_size;
    int Npad = (N + 255) & ~255;

    auto al = [](size_t v) { return (v + 255) & ~(size_t)255; };
    char* ws = (char*)d_ws;
    size_t bins_off   = 0;                               // 128 ints
    size_t cursor_off = al(128 * 4);                     // 128 x stride-16 ints
    size_t gacc_off   = cursor_off + al(128 * 16 * 4);
    size_t bns_off    = gacc_off + al((size_t)G * 46 * 4);
    size_t scl_off    = bns_off + 256;
    size_t zero_end   = scl_off + 256;                   // memset up to here
    size_t es_off     = al(zero_end);
    size_t ed_off     = es_off + al((size_t)E * 4);
    size_t eg_off     = ed_off + al((size_t)E * 4);
    size_t a_off      = eg_off + al((size_t)E * 4);
    size_t b_off      = a_off + al((size_t)Npad * 64 * 2);

    int*   bins   = (int*)(ws + bins_off);
    int*   cursor = (int*)(ws + cursor_off);
    float* gacc   = (float*)(ws + gacc_off);
    float* bns    = (float*)(ws + bns_off);
    float* scl    = (float*)(ws + scl_off);
    int*   es     = (int*)(ws + es_off);
    int*   ed     = (int*)(ws + ed_off);
    int*   eg     = (int*)(ws + eg_off);
    unsigned short* A  = (unsigned short*)(ws + a_off);
    unsigned short* Bm = (unsigned short*)(ws + b_off);

    // zero bins/cursors/gacc/bns/scl (ws poisoned 0xAA before each call)
    hipMemsetAsync(ws, 0, zero_end, stream);

    k_bnstat<<<120, 256, 0, stream>>>(x, N, bns);
    k_bnfin<<<1, 64, 0, stream>>>(bns, bn_g, bn_b, scl, 1.0f / (float)N);
    k_node<<<(N + 127) / 128, 128, 0, stream>>>(x, batch, in_w1, in_b1, in_w2, in_b2,
                                                cw1, cb1, scl, A, Bm, gacc, N);
    k_ghist<<<256, 256, 0, stream>>>(ei, batch, bins, E);
    k_gscan<<<1, 128, 0, stream>>>(bins, cursor);
    k_gscatter<<<512, 256, 0, stream>>>(ei, batch, cursor, es, ed, eg, E);
    k_edge<<<1024, 256, 0, stream>>>(es, ed, eg, A, Bm, cw2, cb2, gacc, E);
    k_out<<<1, 128, 0, stream>>>(gacc, ow1, ob1, ow2, ob2, (float*)d_out, G);
}

// Round 8
// 288.954 us; speedup vs baseline: 2.5603x; 2.5603x over previous
//
#include <hip/hip_runtime.h>

// EdgeNet: BN -> inputnet MLP -> EdgeConv(linearized) -> mean-pool -> output MLP
// N=50000, E=1.6M, D=13, H=32, G=128. All I/O float32.
// EdgeConv restructure: per-node A = feat@(Wtop-Wbot)+b1, B = feat@Wbot (bf16);
// per-edge h = relu(A[dst]+B[src]); msg = tanh(h@W2+b2) via MFMA 16x16x32 bf16,
// scattered to bf16 Hn via global_atomic_pk_add_bf16 (R6 structure; R7's sort
// was a 256us scatter regression -> reverted).
// R8: (a) k_edge processes 2 independent 16-edge groups per iteration (ILP to
//     hide gather latency), grid 2048; (b) launch-count cut: no memset, no
//     k_bnfin -- k_bnstat writes per-block partials + zeroes Hn/gacc, k_node
//     reduces partials and computes BN scale/shift inline.

typedef __attribute__((ext_vector_type(4))) float floatx4;
typedef __attribute__((ext_vector_type(8))) short short8;

__device__ __forceinline__ unsigned short f2bf(float f) {
    unsigned int u = __float_as_uint(f);
    u += 0x7FFFu + ((u >> 16) & 1u);   // RTNE
    return (unsigned short)(u >> 16);
}
__device__ __forceinline__ float bf2f(unsigned short u) {
    return __uint_as_float(((unsigned int)u) << 16);
}
__device__ __forceinline__ float fast_tanh(float x) {
    float ax = fminf(fabsf(x), 20.0f);
    float t = __expf(-2.0f * ax);
    float r = (1.0f - t) / (1.0f + t);
    return copysignf(r, x);
}
__device__ __forceinline__ float fast_sigmoid(float x) {
    float xc = fminf(fmaxf(x, -30.f), 30.f);
    return 1.0f / (1.0f + __expf(-xc));
}
// fire-and-forget packed bf16x2 atomic add (memory-side RMW)
__device__ __forceinline__ void atomic_pk_add_bf16(unsigned short* addr, unsigned int packed) {
    asm volatile("global_atomic_pk_add_bf16 %0, %1, off" :: "v"(addr), "v"(packed) : "memory");
}

#define NBLK_STAT 120

// ---------------- K1: BN partial sums + zero Hn/gacc ----------------
// part[b*32+d] = block b's sum_d ; part[3840 + b*32 + d] = sumsq_d (d<13).
// No atomics -> no pre-zero needed anywhere.
__global__ __launch_bounds__(256) void k_bnstat(const float* __restrict__ x, int N,
                                                float* __restrict__ part,
                                                uint4* __restrict__ HnZ, int hnq,
                                                float* __restrict__ gacc, int gn) {
    int tid = blockIdx.x * blockDim.x + threadIdx.x;
    int stride = gridDim.x * blockDim.x;
    // zero Hn (bf16 zeros) and gacc
    uint4 z4 = make_uint4(0u, 0u, 0u, 0u);
    for (int i = tid; i < hnq; i += stride) HnZ[i] = z4;
    for (int i = tid; i < gn; i += stride) gacc[i] = 0.f;

    float s[13], q[13];
#pragma unroll
    for (int d = 0; d < 13; d++) { s[d] = 0.f; q[d] = 0.f; }
    for (int n = tid; n < N; n += stride) {
        const float* row = x + (size_t)n * 13;
#pragma unroll
        for (int d = 0; d < 13; d++) { float f = row[d]; s[d] += f; q[d] += f * f; }
    }
#pragma unroll
    for (int d = 0; d < 13; d++) {
        for (int off = 32; off > 0; off >>= 1) {
            s[d] += __shfl_down(s[d], off, 64);
            q[d] += __shfl_down(q[d], off, 64);
        }
    }
    __shared__ float red[4][26];
    int w = threadIdx.x >> 6;
    if ((threadIdx.x & 63) == 0) {
#pragma unroll
        for (int d = 0; d < 13; d++) { red[w][d] = s[d]; red[w][13 + d] = q[d]; }
    }
    __syncthreads();
    if (threadIdx.x < 26) {
        float v = red[0][threadIdx.x] + red[1][threadIdx.x] + red[2][threadIdx.x] + red[3][threadIdx.x];
        int d = threadIdx.x;
        if (d < 13) part[blockIdx.x * 32 + d] = v;
        else        part[NBLK_STAT * 32 + blockIdx.x * 32 + (d - 13)] = v;
    }
}

// ---------------- K2: per-node phase ----------------
// phase0: weights -> LDS; BN scale/shift computed inline from partials.
// phase1: per-thread X, h1, h2; feat row -> LDS (bf16, K padded to 64); gacc X-sums
// phase2: 2 waves x MFMA: feat[64x64] @ Wcat[64x128] -> A|B rows (bf16, global)
#define FP 72  // feat LDS row stride in shorts (64 + 8 pad)
#define WP 72  // WcatT LDS row stride in shorts
__global__ __launch_bounds__(128) void k_node(
    const float* __restrict__ x, const int* __restrict__ batch,
    const float* __restrict__ bn_g, const float* __restrict__ bn_b,
    const float* __restrict__ in_w1, const float* __restrict__ in_b1,
    const float* __restrict__ in_w2, const float* __restrict__ in_b2,
    const float* __restrict__ conv_w1, const float* __restrict__ conv_b1,
    const float* __restrict__ part,
    unsigned short* __restrict__ A, unsigned short* __restrict__ Bm,
    float* __restrict__ gacc, int N) {
    __shared__ float sW1[13 * 32], sB1[32], sW2[32 * 32], sB2[32];
    __shared__ float sScl[16], sShf[16];
    __shared__ unsigned short sWcatT[128 * WP];
    __shared__ unsigned short sFeat[128 * FP];
    int tid = threadIdx.x;

    for (int i = tid; i < 13 * 32; i += 128) sW1[i] = in_w1[i];
    if (tid < 32) { sB1[tid] = in_b1[tid]; sB2[tid] = in_b2[tid]; }
    for (int i = tid; i < 32 * 32; i += 128) sW2[i] = in_w2[i];
    for (int i = tid; i < 128 * 64; i += 128) {
        int c = i >> 6, k = i & 63;
        float v = 0.f;
        if (k < 45) {
            int cc = c & 63;
            float bot = conv_w1[(45 + k) * 64 + cc];
            v = (c < 64) ? (conv_w1[k * 64 + cc] - bot) : bot;
        }
        sWcatT[c * WP + k] = f2bf(v);
    }
    if (tid < 13) {
        float su = 0.f, sq = 0.f;
        for (int b = 0; b < NBLK_STAT; b++) {
            su += part[b * 32 + tid];
            sq += part[NBLK_STAT * 32 + b * 32 + tid];
        }
        float invN = 1.0f / (float)N;
        float mu = su * invN;
        float var = fmaxf(sq * invN - mu * mu, 0.f);
        float sc = bn_g[tid] / sqrtf(var + 1e-5f);
        sScl[tid] = sc;
        sShf[tid] = bn_b[tid] - mu * sc;
    }
    __syncthreads();

    int n = blockIdx.x * 128 + tid;
    bool valid = (n < N);
    int nl = valid ? n : (N - 1);

    float X[13];
#pragma unroll
    for (int d = 0; d < 13; d++)
        X[d] = x[(size_t)nl * 13 + d] * sScl[d] + sShf[d];
    float h1[32];
#pragma unroll
    for (int j = 0; j < 32; j++) {
        float acc = sB1[j];
#pragma unroll
        for (int d = 0; d < 13; d++) acc += X[d] * sW1[d * 32 + j];
        h1[j] = fmaxf(acc, 0.f);
    }
    float h2[32];
#pragma unroll
    for (int j = 0; j < 32; j++) {
        float acc = sB2[j];
#pragma unroll
        for (int k = 0; k < 32; k++) acc += h1[k] * sW2[k * 32 + j];
        h2[j] = fast_tanh(acc);
    }

    unsigned int fw[16];
#pragma unroll
    for (int i = 0; i < 16; i++) fw[i] = 0;
    if (valid) {
#pragma unroll
        for (int i = 0; i < 16; i++)
            fw[i] = (unsigned)f2bf(h2[2 * i]) | ((unsigned)f2bf(h2[2 * i + 1]) << 16);
    }
    unsigned int xw[7];
#pragma unroll
    for (int i = 0; i < 7; i++) xw[i] = 0;
    if (valid) {
#pragma unroll
        for (int i = 0; i < 6; i++)
            xw[i] = (unsigned)f2bf(X[2 * i]) | ((unsigned)f2bf(X[2 * i + 1]) << 16);
        xw[6] = (unsigned)f2bf(X[12]);
    }
    {
        unsigned short* row = sFeat + tid * FP;
        ((uint4*)row)[0] = make_uint4(fw[0], fw[1], fw[2], fw[3]);
        ((uint4*)row)[1] = make_uint4(fw[4], fw[5], fw[6], fw[7]);
        ((uint4*)row)[2] = make_uint4(fw[8], fw[9], fw[10], fw[11]);
        ((uint4*)row)[3] = make_uint4(fw[12], fw[13], fw[14], fw[15]);
        ((uint4*)row)[4] = make_uint4(xw[0], xw[1], xw[2], xw[3]);
        ((uint4*)row)[5] = make_uint4(xw[4], xw[5], xw[6], 0u);
        ((uint4*)row)[6] = make_uint4(0u, 0u, 0u, 0u);
        ((uint4*)row)[7] = make_uint4(0u, 0u, 0u, 0u);
    }

    {
        int g = valid ? batch[n] : -1;
        unsigned long long uni = __ballot(g == __shfl(g, 0, 64));
        if (uni == ~0ull && g >= 0) {
            float red[14];
#pragma unroll
            for (int d = 0; d < 13; d++) red[d] = X[d];
            red[13] = 1.0f;
#pragma unroll
            for (int d = 0; d < 14; d++)
                for (int off = 32; off > 0; off >>= 1)
                    red[d] += __shfl_down(red[d], off, 64);
            if ((tid & 63) == 0) {
#pragma unroll
                for (int d = 0; d < 13; d++) unsafeAtomicAdd(&gacc[g * 46 + 32 + d], red[d]);
                unsafeAtomicAdd(&gacc[g * 46 + 45], red[13]);
            }
        } else if (valid) {
#pragma unroll
            for (int d = 0; d < 13; d++) unsafeAtomicAdd(&gacc[g * 46 + 32 + d], X[d]);
            unsafeAtomicAdd(&gacc[g * 46 + 45], 1.0f);
        }
    }
    __syncthreads();

    int lane = tid & 63;
    int w = tid >> 6;
    int q = lane >> 4;
    int m = lane & 15;

    short8 wf[2][8];
#pragma unroll
    for (int ks = 0; ks < 2; ks++)
#pragma unroll
        for (int t = 0; t < 8; t++) {
            wf[ks][t] = *(const short8*)(sWcatT + (t * 16 + m) * WP + ks * 32 + q * 8);
        }
    float cb1v[4];
#pragma unroll
    for (int t = 0; t < 4; t++) cb1v[t] = conv_b1[t * 16 + m];

    int base = blockIdx.x * 128 + w * 64;
#pragma unroll
    for (int tile = 0; tile < 4; tile++) {
        const unsigned short* ar = sFeat + (w * 64 + tile * 16 + m) * FP;
        short8 a0 = *(const short8*)(ar + q * 8);
        short8 a1 = *(const short8*)(ar + 32 + q * 8);
        floatx4 c[8];
#pragma unroll
        for (int t = 0; t < 8; t++) {
            floatx4 z = {0.f, 0.f, 0.f, 0.f};
            c[t] = __builtin_amdgcn_mfma_f32_16x16x32_bf16(a0, wf[0][t], z, 0, 0, 0);
            c[t] = __builtin_amdgcn_mfma_f32_16x16x32_bf16(a1, wf[1][t], c[t], 0, 0, 0);
        }
#pragma unroll
        for (int r = 0; r < 4; r++) {
            int row = base + tile * 16 + (q << 2) + r;
            if (row < N) {
#pragma unroll
                for (int t = 0; t < 4; t++)
                    A[(size_t)row * 64 + t * 16 + m] = f2bf(c[t][r] + cb1v[t]);
#pragma unroll
                for (int t = 4; t < 8; t++)
                    Bm[(size_t)row * 64 + (t - 4) * 16 + m] = f2bf(c[t][r]);
            }
        }
    }
}

// ---------------- K3: edge phase (MFMA + packed bf16 atomics, 2-group ILP) --
// Two independent 16-edge groups per iteration to hide gather latency.
// B-frags hold W2 cols interleaved even/odd so lane (q,m)'s C pair is
// channels (2m,2m+1) of edge e0+4q+r -> ONE pk_add_bf16 per pair.
__global__ __launch_bounds__(256) void k_edge(
    const int* __restrict__ ei,
    const unsigned short* __restrict__ A, const unsigned short* __restrict__ Bm,
    const float* __restrict__ conv_w2, const float* __restrict__ conv_b2,
    unsigned short* __restrict__ Hn, int E) {
    int lane = threadIdx.x & 63;
    int wid  = blockIdx.x * (blockDim.x >> 6) + (threadIdx.x >> 6);
    int nw   = gridDim.x * (blockDim.x >> 6);
    int q = lane >> 4;
    int m = lane & 15;

    short8 wf[2][2];
#pragma unroll
    for (int s = 0; s < 2; s++)
#pragma unroll
        for (int t = 0; t < 2; t++)
#pragma unroll
            for (int j = 0; j < 8; j++)
                wf[s][t][j] = (short)f2bf(conv_w2[(s * 32 + q * 8 + j) * 32 + 2 * m + t]);
    float cb2a = conv_b2[2 * m];
    float cb2b = conv_b2[2 * m + 1];

    const int* srcp = ei;
    const int* dstp = ei + E;
    int npairs = E >> 5;           // pairs of 16-edge groups

    for (int p = wid; p < npairs; p += nw) {
        int e0 = p << 5;
        // ---- load both groups' indices ----
        int vd0 = dstp[e0 + m];
        int vs0 = srcp[e0 + m];
        int vd1 = dstp[e0 + 16 + m];
        int vs1 = srcp[e0 + 16 + m];
        // ---- gather A/B for both groups (8 independent 16B loads) ----
        uint4 av0a = *(const uint4*)(A  + (size_t)vd0 * 64 + q * 8);
        uint4 av0b = *(const uint4*)(A  + (size_t)vd0 * 64 + 32 + q * 8);
        uint4 bv0a = *(const uint4*)(Bm + (size_t)vs0 * 64 + q * 8);
        uint4 bv0b = *(const uint4*)(Bm + (size_t)vs0 * 64 + 32 + q * 8);
        uint4 av1a = *(const uint4*)(A  + (size_t)vd1 * 64 + q * 8);
        uint4 av1b = *(const uint4*)(A  + (size_t)vd1 * 64 + 32 + q * 8);
        uint4 bv1a = *(const uint4*)(Bm + (size_t)vs1 * 64 + q * 8);
        uint4 bv1b = *(const uint4*)(Bm + (size_t)vs1 * 64 + 32 + q * 8);

        floatx4 c00 = {0.f, 0.f, 0.f, 0.f}, c01 = {0.f, 0.f, 0.f, 0.f};
        floatx4 c10 = {0.f, 0.f, 0.f, 0.f}, c11 = {0.f, 0.f, 0.f, 0.f};

        auto mk = [](uint4 av, uint4 bv) -> short8 {
            unsigned au[4] = {av.x, av.y, av.z, av.w};
            unsigned bu[4] = {bv.x, bv.y, bv.z, bv.w};
            short8 ha;
#pragma unroll
            for (int i = 0; i < 4; i++) {
                float a0 = __uint_as_float(au[i] << 16);
                float a1 = __uint_as_float(au[i] & 0xffff0000u);
                float b0 = __uint_as_float(bu[i] << 16);
                float b1 = __uint_as_float(bu[i] & 0xffff0000u);
                float h0 = fmaxf(a0 + b0, 0.f);
                float h1v = fmaxf(a1 + b1, 0.f);
                ha[2 * i]     = (short)(f2bf(h0));
                ha[2 * i + 1] = (short)(f2bf(h1v));
            }
            return ha;
        };
        short8 h0a = mk(av0a, bv0a);
        short8 h0b = mk(av0b, bv0b);
        short8 h1a = mk(av1a, bv1a);
        short8 h1b = mk(av1b, bv1b);

        c00 = __builtin_amdgcn_mfma_f32_16x16x32_bf16(h0a, wf[0][0], c00, 0, 0, 0);
        c01 = __builtin_amdgcn_mfma_f32_16x16x32_bf16(h0a, wf[0][1], c01, 0, 0, 0);
        c10 = __builtin_amdgcn_mfma_f32_16x16x32_bf16(h1a, wf[0][0], c10, 0, 0, 0);
        c11 = __builtin_amdgcn_mfma_f32_16x16x32_bf16(h1a, wf[0][1], c11, 0, 0, 0);
        c00 = __builtin_amdgcn_mfma_f32_16x16x32_bf16(h0b, wf[1][0], c00, 0, 0, 0);
        c01 = __builtin_amdgcn_mfma_f32_16x16x32_bf16(h0b, wf[1][1], c01, 0, 0, 0);
        c10 = __builtin_amdgcn_mfma_f32_16x16x32_bf16(h1b, wf[1][0], c10, 0, 0, 0);
        c11 = __builtin_amdgcn_mfma_f32_16x16x32_bf16(h1b, wf[1][1], c11, 0, 0, 0);

#pragma unroll
        for (int r = 0; r < 4; r++) {
            int m2 = (q << 2) + r;
            int dd0 = __shfl(vd0, m2, 64);
            int dd1 = __shfl(vd1, m2, 64);
            float o00 = fast_tanh(c00[r] + cb2a);
            float o01 = fast_tanh(c01[r] + cb2b);
            float o10 = fast_tanh(c10[r] + cb2a);
            float o11 = fast_tanh(c11[r] + cb2b);
            unsigned pk0 = (unsigned)f2bf(o00) | ((unsigned)f2bf(o01) << 16);
            unsigned pk1 = (unsigned)f2bf(o10) | ((unsigned)f2bf(o11) << 16);
            atomic_pk_add_bf16(Hn + (size_t)dd0 * 32 + 2 * m, pk0);
            atomic_pk_add_bf16(Hn + (size_t)dd1 * 32 + 2 * m, pk1);
        }
    }

    // tail: edges beyond the last full 32-pair (covers E%32)
    int tstart = npairs << 5;
    int tail = E - tstart;
    if (tail && wid == 0 && lane < tail) {
        int e = tstart + lane;
        int vd = dstp[e], vs = srcp[e];
        float h[64];
        for (int k = 0; k < 64; k++) {
            float a = bf2f(A[(size_t)vd * 64 + k]);
            float b = bf2f(Bm[(size_t)vs * 64 + k]);
            h[k] = fmaxf(a + b, 0.f);
        }
        for (int j = 0; j < 16; j++) {
            float acc0 = conv_b2[2 * j], acc1 = conv_b2[2 * j + 1];
            for (int k = 0; k < 64; k++) {
                acc0 += h[k] * conv_w2[k * 32 + 2 * j];
                acc1 += h[k] * conv_w2[k * 32 + 2 * j + 1];
            }
            unsigned pk = (unsigned)f2bf(fast_tanh(acc0)) | ((unsigned)f2bf(fast_tanh(acc1)) << 16);
            atomic_pk_add_bf16(Hn + (size_t)vd * 32 + 2 * j, pk);
        }
    }
}

// ---------------- K4: pool bf16 Hn into graph accumulators ----------------
__global__ __launch_bounds__(256) void k_pool(const unsigned short* __restrict__ Hn,
                                              const int* __restrict__ batch,
                                              float* __restrict__ gacc, int N) {
    const int NPB = 512;
    int c = threadIdx.x & 31;
    int r = threadIdx.x >> 5;  // 0..7
    int n0 = blockIdx.x * NPB;
    int nend = min(n0 + NPB, N);
    int gcur = -1;
    float acc = 0.f;
    for (int n = n0 + r; n < nend; n += 8) {
        int g = batch[n];
        if (g != gcur) {
            if (gcur >= 0) unsafeAtomicAdd(&gacc[gcur * 46 + c], acc);
            gcur = g; acc = 0.f;
        }
        acc += bf2f(Hn[(size_t)n * 32 + c]);
    }
    if (gcur >= 0) unsafeAtomicAdd(&gacc[gcur * 46 + c], acc);
}

// ---------------- K5: output MLP ----------------
__global__ void k_out(const float* __restrict__ gacc,
                      const float* __restrict__ out_w1, const float* __restrict__ out_b1,
                      const float* __restrict__ out_w2, const float* __restrict__ out_b2,
                      float* __restrict__ out, int G) {
    int g = blockIdx.x * blockDim.x + threadIdx.x;
    if (g >= G) return;
    float cnt = fmaxf(gacc[g * 46 + 45], 1.0f);
    float inv = 1.0f / cnt;
    float f[45];
#pragma unroll
    for (int i = 0; i < 45; i++) f[i] = gacc[g * 46 + i] * inv;
    float h[32];
#pragma unroll
    for (int j = 0; j < 32; j++) {
        float acc = out_b1[j];
#pragma unroll
        for (int k = 0; k < 45; k++) acc += f[k] * out_w1[k * 32 + j];
        h[j] = fmaxf(acc, 0.f);
    }
    float o = out_b2[0];
#pragma unroll
    for (int j = 0; j < 32; j++) o += h[j] * out_w2[j];
    out[g] = fast_sigmoid(o);
}

extern "C" void kernel_launch(void* const* d_in, const int* in_sizes, int n_in,
                              void* d_out, int out_size, void* d_ws, size_t ws_size,
                              hipStream_t stream) {
    const float* x      = (const float*)d_in[0];
    const int*   ei     = (const int*)d_in[1];
    const int*   batch  = (const int*)d_in[2];
    const float* bn_g   = (const float*)d_in[3];
    const float* bn_b   = (const float*)d_in[4];
    const float* in_w1  = (const float*)d_in[5];
    const float* in_b1  = (const float*)d_in[6];
    const float* in_w2  = (const float*)d_in[7];
    const float* in_b2  = (const float*)d_in[8];
    const float* cw1    = (const float*)d_in[9];
    const float* cb1    = (const float*)d_in[10];
    const float* cw2    = (const float*)d_in[11];
    const float* cb2    = (const float*)d_in[12];
    const float* ow1    = (const float*)d_in[13];
    const float* ob1    = (const float*)d_in[14];
    const float* ow2    = (const float*)d_in[15];
    const float* ob2    = (const float*)d_in[16];

    int N = in_sizes[0] / 13;
    int E = in_sizes[1] / 2;
    int G = out_size;
    int Npad = (N + 255) & ~255;

    auto al = [](size_t v) { return (v + 255) & ~(size_t)255; };
    char* ws = (char*)d_ws;
    size_t hn_off   = 0;                                  // Hn: bf16 [N][32]
    size_t gacc_off = al((size_t)N * 32 * 2);
    size_t part_off = gacc_off + al((size_t)G * 46 * 4);
    size_t a_off    = part_off + al(2 * NBLK_STAT * 32 * 4);
    size_t b_off    = a_off + al((size_t)Npad * 64 * 2);

    unsigned short* Hn = (unsigned short*)(ws + hn_off);
    float* gacc = (float*)(ws + gacc_off);
    float* part = (float*)(ws + part_off);
    unsigned short* A  = (unsigned short*)(ws + a_off);
    unsigned short* Bm = (unsigned short*)(ws + b_off);

    int hnq = (N * 32 * 2) / 16;        // Hn size in uint4s (N*64 bytes)
    int gn  = G * 46;

    k_bnstat<<<NBLK_STAT, 256, 0, stream>>>(x, N, part, (uint4*)Hn, hnq, gacc, gn);
    k_node<<<(N + 127) / 128, 128, 0, stream>>>(x, batch, bn_g, bn_b,
                                                in_w1, in_b1, in_w2, in_b2,
                                                cw1, cb1, part, A, Bm, gacc, N);
    k_edge<<<2048, 256, 0, stream>>>(ei, A, Bm, cw2, cb2, Hn, E);
    k_pool<<<(N + 511) / 512, 256, 0, stream>>>(Hn, batch, gacc, N);
    k_out<<<1, 128, 0, stream>>>(gacc, ow1, ob1, ow2, ob2, (float*)d_out, G);
}